// Round 10
// baseline (152.879 us; speedup 1.0000x reference)
//
#include <hip/hip_runtime.h>
#include <hip/hip_bf16.h>

#define NKV 8
#define NHEADS 32
#define HDIM 128
#define BATCH 512
#define CACHE 2048
#define CTX_TOT 2560           // CACHE + BATCH
#define CT 32                  // context tile (columns per iteration; halved for dbuf)
#define SPLITS 6               // flash-decoding context splits
#define PP 40                  // P_lds row pitch (32 + 8 pad)
#define NEG_BIG (-1e30f)

typedef __attribute__((ext_vector_type(8))) _Float16 half8;
typedef __attribute__((ext_vector_type(4))) float floatx4;

// async global->LDS DMA, 16 B per lane; LDS dest = wave-uniform base + lane*16
static __device__ __forceinline__ void dma16(const void* g, void* l) {
    __builtin_amdgcn_global_load_lds((const __attribute__((address_space(1))) void*)g,
                                     (__attribute__((address_space(3))) void*)l,
                                     16, 0, 0);
}

// ================= fused preprocess kernel =================
// 1664 blocks x 256 threads:
//   [0,512)     kprep: ktc [kv][128d][2048c] f32 -> Kh [kv][c][d] f16   (tile 32c x 128d)
//   [512,1024)  vprep: vc  [kv][2048c][128d] f32 -> Vth [kv][d][c] f16  (tile 128c x 32d)
//   [1024,1536) knew : keys*kq -> outk f32 + Kh rows 2048..2559
//   [1536,1664) vnew : clamp(values) -> outv f32 + Vth cols 2048..2559  (tile 128b x 32d)
__global__ __launch_bounds__(256) void prep(const float* __restrict__ ktc,
                                            const float* __restrict__ vc,
                                            const float* __restrict__ keys,
                                            const float* __restrict__ values,
                                            const float* __restrict__ kq,
                                            float* __restrict__ outk,
                                            float* __restrict__ outv,
                                            _Float16* __restrict__ Kh,
                                            _Float16* __restrict__ Vth) {
    __shared__ float tile[128 * 33];                  // [src_row][33] padded
    const int bid = blockIdx.x;
    const int t = threadIdx.x;

    if (bid < 512) {
        // ---- kprep: tile = full 128 d x 32 c ----
        int c0 = (bid & 63) * 32, kv = bid >> 6;
        const float* src = ktc + (size_t)kv * HDIM * CACHE + c0;
#pragma unroll
        for (int i = 0; i < 4; i++) {
            int idx = t + 256 * i;                    // 0..1023
            int d = idx >> 3, cc = idx & 7;           // 8 chunks of 4 c
            float4 v = *(const float4*)(src + (size_t)d * CACHE + cc * 4);
            *(float4*)(&tile[d * 33 + cc * 4]) = v;   // tile[d][c]
        }
        __syncthreads();
        _Float16* dst = Kh + ((size_t)kv * CTX_TOT + c0) * HDIM;
#pragma unroll
        for (int i = 0; i < 2; i++) {
            int c = (t >> 4) + 16 * i, dg = t & 15;   // lane writes 8 d (16B)
            half8 o;
#pragma unroll
            for (int k = 0; k < 8; k++) o[k] = (_Float16)tile[(dg * 8 + k) * 33 + c];
            *(half8*)(dst + (size_t)c * HDIM + dg * 8) = o;
        }
    } else if (bid < 1024) {
        // ---- vprep: tile = 128 c x 32 d ----
        int l = bid - 512;
        int c1 = (l & 15) * 128, d0 = ((l >> 4) & 3) * 32, kv = l >> 6;
        const float* src = vc + ((size_t)kv * CACHE + c1) * HDIM + d0;
#pragma unroll
        for (int i = 0; i < 4; i++) {
            int idx = t + 256 * i;
            int c = idx >> 3, dc = idx & 7;
            float4 v = *(const float4*)(src + (size_t)c * HDIM + dc * 4);
            *(float4*)(&tile[c * 33 + dc * 4]) = v;   // tile[c][d]
        }
        __syncthreads();
        _Float16* dst = Vth + ((size_t)kv * HDIM + d0) * CTX_TOT + c1;
#pragma unroll
        for (int i = 0; i < 2; i++) {
            int d = (t >> 4) + 16 * i, cg = t & 15;   // lane writes 8 c (16B)
            half8 o;
#pragma unroll
            for (int k = 0; k < 8; k++) o[k] = (_Float16)tile[(cg * 8 + k) * 33 + d];
            *(half8*)(dst + (size_t)d * CTX_TOT + cg * 8) = o;
        }
    } else if (bid < 1536) {
        // ---- knew: 4 f32 per thread ----
        int base = ((bid - 1024) * 256 + t) * 4;      // 0..2097151, 4-aligned
        float s = kq[0];
        float4 v = *(const float4*)(keys + base);
        v.x *= s; v.y *= s; v.z *= s; v.w *= s;
        *(float4*)(outk + base) = v;
        int kv = base >> 16;
        int rem = base & 0xFFFF;
        _Float16* dst = Kh + ((size_t)kv * CTX_TOT + CACHE) * HDIM + rem;
        dst[0] = (_Float16)v.x; dst[1] = (_Float16)v.y;
        dst[2] = (_Float16)v.z; dst[3] = (_Float16)v.w;
    } else {
        // ---- vnew: tile = 128 b x 32 d, clamp + outv in phase 1 ----
        int l = bid - 1536;
        int b1 = (l & 3) * 128, d0 = ((l >> 2) & 3) * 32, kv = l >> 4;
        const float* src = values + ((size_t)kv * BATCH + b1) * HDIM + d0;
        float* dst32 = outv + ((size_t)kv * BATCH + b1) * HDIM + d0;
#pragma unroll
        for (int i = 0; i < 4; i++) {
            int idx = t + 256 * i;
            int b = idx >> 3, dc = idx & 7;
            float4 v = *(const float4*)(src + (size_t)b * HDIM + dc * 4);
            v.x = fmaxf(v.x, -10000.0f); v.y = fmaxf(v.y, -10000.0f);
            v.z = fmaxf(v.z, -10000.0f); v.w = fmaxf(v.w, -10000.0f);
            *(float4*)(dst32 + (size_t)b * HDIM + dc * 4) = v;
            *(float4*)(&tile[b * 33 + dc * 4]) = v;   // tile[b][d]
        }
        __syncthreads();
        _Float16* dst = Vth + ((size_t)kv * HDIM + d0) * CTX_TOT + CACHE + b1;
#pragma unroll
        for (int i = 0; i < 2; i++) {
            int d = (t >> 4) + 16 * i, bg = t & 15;   // lane writes 8 b (16B)
            half8 o;
#pragma unroll
            for (int k = 0; k < 8; k++) o[k] = (_Float16)tile[(bg * 8 + k) * 33 + d];
            *(half8*)(dst + (size_t)d * CTX_TOT + bg * 8) = o;
        }
    }
}

// ================= split flash-attention kernel =================
// grid (128, SPLITS): blockIdx.x = h + 32*qb2 (128-row q block), blockIdx.y = s
// Each wave: 2 q sub-tiles (rows [qr0,qr0+15], [qr0+64,qr0+79]); S computed
// sequentially per half (r9). NEW: CT=32 + 2-deep LDS double-buffer — DMA for
// tile t+1 is issued BEFORE computing tile t, so the mandatory vmcnt(0) at the
// end-of-iter barrier waits on a transfer that has been in flight for the whole
// compute phase (~1400 cyc > ~900 cyc HBM latency). Breaks the r6/r9 convoy.
__global__ __launch_bounds__(256, 3) void attn_split(const float* __restrict__ q_g,
                                                     const _Float16* __restrict__ Kh,
                                                     const _Float16* __restrict__ Vth,
                                                     _Float16* __restrict__ Opart,
                                                     float* __restrict__ MLpart) {
    __shared__ _Float16 Klds[2][CT * 128];          // [c][d] swizzled, 2 x 8 KB
    __shared__ _Float16 Vlds[2][128 * CT];          // [d][c] swizzled, 2 x 8 KB
    __shared__ _Float16 Plds[4][32 * PP];           // per-wave, 2 halves x 16 q, 10 KB

    const int h = blockIdx.x & 31;
    const int qb2 = blockIdx.x >> 5;                  // 0..3 (128-row blocks)
    const int s = blockIdx.y;                         // 0..5
    const int kv = h >> 2;
    const int t = threadIdx.x;
    const int wave = t >> 6;
    const int lane = t & 63;
    const int l15 = lane & 15, quad = lane >> 4;

    const float LOG2E = 1.44269504088896340736f;
    const int qrow0 = qb2 * 128 + wave * 16;          // half0; half1 = +64

    const _Float16* kg = Kh + (size_t)kv * CTX_TOT * HDIM;
    const _Float16* vg = Vth + (size_t)kv * HDIM * CTX_TOT;

    half8 qfrag[2][4];
#pragma unroll
    for (int hh = 0; hh < 2; hh++) {
        const float* qp = q_g + ((size_t)h * BATCH + qrow0 + hh * 64 + l15) * HDIM + quad * 8;
#pragma unroll
        for (int kb = 0; kb < 4; kb++) {
            const float* p = qp + kb * 32;
            float4 a = *(const float4*)p;
            float4 b = *(const float4*)(p + 4);
            qfrag[hh][kb][0] = (_Float16)(a.x * LOG2E); qfrag[hh][kb][1] = (_Float16)(a.y * LOG2E);
            qfrag[hh][kb][2] = (_Float16)(a.z * LOG2E); qfrag[hh][kb][3] = (_Float16)(a.w * LOG2E);
            qfrag[hh][kb][4] = (_Float16)(b.x * LOG2E); qfrag[hh][kb][5] = (_Float16)(b.y * LOG2E);
            qfrag[hh][kb][6] = (_Float16)(b.z * LOG2E); qfrag[hh][kb][7] = (_Float16)(b.w * LOG2E);
        }
    }

    floatx4 O[2][8];
#pragma unroll
    for (int hh = 0; hh < 2; hh++)
#pragma unroll
        for (int nb = 0; nb < 8; nb++) O[hh][nb] = (floatx4){0.f, 0.f, 0.f, 0.f};
    float m_r[2][4], l_r[2][4];
#pragma unroll
    for (int hh = 0; hh < 2; hh++)
#pragma unroll
        for (int r = 0; r < 4; r++) { m_r[hh][r] = NEG_BIG; l_r[hh][r] = 0.f; }

    const int nT = 68 + 4 * qb2;                      // CT=32 tiles

    // stage tile ttile into buffer b (8 async DMA instrs per wave total)
    auto stage = [&](int ttile, int b) {
        const int c0s = ttile * CT;
#pragma unroll
        for (int j = 0; j < 2; j++) {                 // K: 32 rows x 128 d
            int row = wave * 8 + j * 4 + (lane >> 4);
            int gch = (lane & 15) ^ (row & 7);
            dma16(kg + (size_t)(c0s + row) * HDIM + gch * 8,
                  &Klds[b][(wave * 8 + j * 4) * 128]);
        }
#pragma unroll
        for (int j = 0; j < 2; j++) {                 // V^T: 128 rows x 32 c
            int row = wave * 32 + j * 16 + (lane >> 2);
            int gch = (lane & 3) ^ (row & 3);
            dma16(vg + (size_t)row * CTX_TOT + c0s + gch * 8,
                  &Vlds[b][(wave * 32 + j * 16) * CT]);
        }
    };

    // ---- pipeline prologue ----
    stage(s, 0);
    __syncthreads();                                  // drain first DMA set
    int buf = 0;

    for (int tt = s; tt < nT; tt += SPLITS) {
        const int c0 = tt * CT;
        // issue next tile's DMA immediately — in flight across compute(t)
        if (tt + SPLITS < nT) stage(tt + SPLITS, buf ^ 1);

        if (c0 <= CACHE + qrow0 + 64 + 15) {          // half1 (or both) active
            // ---- per half: S = Q K^T, softmax, P ----
#pragma unroll
            for (int hh = 0; hh < 2; hh++) {
                const int qr0h = qrow0 + hh * 64;
                if (c0 <= CACHE + qr0h + 15) {        // half active
                    floatx4 S[2];
#pragma unroll
                    for (int cs = 0; cs < 2; cs++) {
                        floatx4 a0 = (floatx4){0.f, 0.f, 0.f, 0.f};
                        int crow = cs * 16 + l15;
#pragma unroll
                        for (int kb = 0; kb < 4; kb++) {
                            half8 kf = *(const half8*)(&Klds[buf][crow * 128 +
                                                       (((kb * 4 + quad) ^ (crow & 7)) << 3)]);
                            a0 = __builtin_amdgcn_mfma_f32_16x16x32_f16(qfrag[hh][kb], kf, a0, 0, 0, 0);
                        }
                        S[cs] = a0;
                    }
                    // mask (only near-diagonal tiles)
                    if (c0 + CT > CACHE + qr0h) {
#pragma unroll
                        for (int cs = 0; cs < 2; cs++)
#pragma unroll
                            for (int r = 0; r < 4; r++) {
                                int c = c0 + cs * 16 + l15;
                                if (c > CACHE + qr0h + quad * 4 + r) S[cs][r] = NEG_BIG;
                            }
                    }
                    float tmax[4];
#pragma unroll
                    for (int r = 0; r < 4; r++)
                        tmax[r] = fmaxf(S[0][r], S[1][r]);
#pragma unroll
                    for (int off = 8; off >= 1; off >>= 1)
#pragma unroll
                        for (int r = 0; r < 4; r++)
                            tmax[r] = fmaxf(tmax[r], __shfl_xor(tmax[r], off, 64));
                    // rescale only when some row's max actually rose
                    bool ch = false;
#pragma unroll
                    for (int r = 0; r < 4; r++) ch = ch || (tmax[r] > m_r[hh][r]);
                    if (__any(ch)) {
#pragma unroll
                        for (int r = 0; r < 4; r++) {
                            float mn = fmaxf(m_r[hh][r], tmax[r]);
                            float alpha = __builtin_amdgcn_exp2f(m_r[hh][r] - mn);
                            m_r[hh][r] = mn;
                            l_r[hh][r] *= alpha;
#pragma unroll
                            for (int nb = 0; nb < 8; nb++) O[hh][nb][r] *= alpha;
                        }
                    }
#pragma unroll
                    for (int cs = 0; cs < 2; cs++)
#pragma unroll
                        for (int r = 0; r < 4; r++) {
                            float p = __builtin_amdgcn_exp2f(S[cs][r] - m_r[hh][r]);
                            l_r[hh][r] += p;
                            Plds[wave][(hh * 16 + quad * 4 + r) * PP + cs * 16 + l15] = (_Float16)p;
                        }
                } else {
                    // half fully masked this tile: zero its P slab
#pragma unroll
                    for (int cs = 0; cs < 2; cs++)
#pragma unroll
                        for (int r = 0; r < 4; r++)
                            Plds[wave][(hh * 16 + quad * 4 + r) * PP + cs * 16 + l15] = (_Float16)0.f;
                }
            }
            // ---- O += P V (single k-step, V fragments shared across halves) ----
            {
                half8 pf0 = *(const half8*)(&Plds[wave][l15 * PP + quad * 8]);
                half8 pf1 = *(const half8*)(&Plds[wave][(16 + l15) * PP + quad * 8]);
#pragma unroll
                for (int nb = 0; nb < 8; nb++) {
                    int vrow = nb * 16 + l15;
                    half8 vf = *(const half8*)(&Vlds[buf][vrow * CT +
                                                         ((quad ^ (vrow & 3)) << 3)]);
                    O[0][nb] = __builtin_amdgcn_mfma_f32_16x16x32_f16(pf0, vf, O[0][nb], 0, 0, 0);
                    O[1][nb] = __builtin_amdgcn_mfma_f32_16x16x32_f16(pf1, vf, O[1][nb], 0, 0, 0);
                }
            }
        }

        __syncthreads();        // drains DMA(t+1) (overlapped) + publishes buffers
        buf ^= 1;
    }

    // ---- epilogue: reduce l across column lanes; write f16 partials + (m,l) ----
#pragma unroll
    for (int hh = 0; hh < 2; hh++)
#pragma unroll
        for (int off = 8; off >= 1; off >>= 1)
#pragma unroll
            for (int r = 0; r < 4; r++) l_r[hh][r] += __shfl_xor(l_r[hh][r], off, 64);

    const size_t rowbase = (size_t)s * NHEADS * BATCH + (size_t)h * BATCH;
#pragma unroll
    for (int hh = 0; hh < 2; hh++) {
#pragma unroll
        for (int nb = 0; nb < 8; nb++)
#pragma unroll
            for (int r = 0; r < 4; r++) {
                int brow = qrow0 + hh * 64 + quad * 4 + r;
                Opart[(rowbase + brow) * HDIM + nb * 16 + l15] = (_Float16)O[hh][nb][r];
            }
        if (l15 == 0) {
#pragma unroll
            for (int r = 0; r < 4; r++) {
                int brow = qrow0 + hh * 64 + quad * 4 + r;
                MLpart[(rowbase + brow) * 2 + 0] = m_r[hh][r];
                MLpart[(rowbase + brow) * 2 + 1] = l_r[hh][r];
            }
        }
    }
}

// ================= merge kernel =================
// 8192 blocks x 256 threads; each block merges 2 rows x 128 d over SPLITS
__global__ __launch_bounds__(256) void attn_merge(const _Float16* __restrict__ Opart,
                                                  const float* __restrict__ MLpart,
                                                  float* __restrict__ out) {
    const int t = threadIdx.x;
    const int row = blockIdx.x * 2 + (t >> 7);
    const int d = t & 127;
    const size_t stride = (size_t)NHEADS * BATCH;     // 16384 rows per split

    float m[SPLITS], l[SPLITS];
    float mm = NEG_BIG;
#pragma unroll
    for (int s = 0; s < SPLITS; s++) {
        m[s] = MLpart[((size_t)s * stride + row) * 2];
        l[s] = MLpart[((size_t)s * stride + row) * 2 + 1];
        mm = fmaxf(mm, m[s]);
    }
    float denom = 0.f, acc = 0.f;
#pragma unroll
    for (int s = 0; s < SPLITS; s++) {
        float w = __builtin_amdgcn_exp2f(m[s] - mm);
        denom += w * l[s];
        acc += w * (float)Opart[((size_t)s * stride + row) * HDIM + d];
    }
    out[(size_t)row * HDIM + d] = acc / denom;
}

// ================= launch =================
extern "C" void kernel_launch(void* const* d_in, const int* in_sizes, int n_in,
                              void* d_out, int out_size, void* d_ws, size_t ws_size,
                              hipStream_t stream) {
    const float* queries = (const float*)d_in[0];
    const float* keys    = (const float*)d_in[1];
    const float* ktc     = (const float*)d_in[2];
    const float* values  = (const float*)d_in[3];
    const float* vcache  = (const float*)d_in[4];
    // d_in[5] = attn_bias: analytic causal mask, not read
    const float* kq      = (const float*)d_in[6];

    float* out     = (float*)d_out;
    float* out_sk  = out + (size_t)NHEADS * BATCH * HDIM;              // scaled_keys
    float* out_sv  = out_sk + (size_t)NKV * BATCH * HDIM;              // scaled_values

    _Float16* Kh   = (_Float16*)d_ws;                                  // [8][2560][128]
    _Float16* Vth  = Kh + (size_t)NKV * CTX_TOT * HDIM;                // [8][128][2560]
    _Float16* Opart = Vth + (size_t)NKV * HDIM * CTX_TOT;              // [6][16384][128] f16
    float*    MLpart = (float*)(Opart + (size_t)SPLITS * NHEADS * BATCH * HDIM); // [6][16384][2]

    prep<<<dim3(1664), dim3(256), 0, stream>>>(ktc, vcache, keys, values, kq,
                                               out_sk, out_sv, Kh, Vth);
    attn_split<<<dim3(128, SPLITS), dim3(256), 0, stream>>>(queries, Kh, Vth, Opart, MLpart);
    attn_merge<<<dim3(8192), dim3(256), 0, stream>>>(Opart, MLpart, out);
}

// Round 12
// 145.174 us; speedup vs baseline: 1.0531x; 1.0531x over previous
//
#include <hip/hip_runtime.h>
#include <hip/hip_bf16.h>

#define NKV 8
#define NHEADS 32
#define HDIM 128
#define BATCH 512
#define CACHE 2048
#define CTX_TOT 2560           // CACHE + BATCH
#define CT 64                  // context tile (columns per iteration)
#define SPLITS 6               // flash-decoding context splits
#define KPITCH 128             // K_lds row pitch (unpadded; XOR-swizzled chunks)
#define VPITCH 64              // V_lds row pitch (unpadded; XOR-swizzled chunks)
#define PPITCH 72              // P_lds row pitch (64 + 8 pad)
#define NEG_BIG (-1e30f)

typedef __attribute__((ext_vector_type(8))) _Float16 half8;
typedef __attribute__((ext_vector_type(4))) float floatx4;

// async global->LDS DMA, 16 B per lane; LDS dest = wave-uniform base + lane*16
static __device__ __forceinline__ void dma16(const void* g, void* l) {
    __builtin_amdgcn_global_load_lds((const __attribute__((address_space(1))) void*)g,
                                     (__attribute__((address_space(3))) void*)l,
                                     16, 0, 0);
}

// ================= fused preprocess kernel =================
// 1664 blocks x 256 threads:
//   [0,512)     kprep: ktc [kv][128d][2048c] f32 -> Kh [kv][c][d] f16   (tile 32c x 128d)
//   [512,1024)  vprep: vc  [kv][2048c][128d] f32 -> Vth [kv][d][c] f16  (tile 128c x 32d)
//   [1024,1536) knew : keys*kq -> outk f32 + Kh rows 2048..2559
//   [1536,1664) vnew : clamp(values) -> outv f32 + Vth cols 2048..2559  (tile 128b x 32d)
__global__ __launch_bounds__(256) void prep(const float* __restrict__ ktc,
                                            const float* __restrict__ vc,
                                            const float* __restrict__ keys,
                                            const float* __restrict__ values,
                                            const float* __restrict__ kq,
                                            float* __restrict__ outk,
                                            float* __restrict__ outv,
                                            _Float16* __restrict__ Kh,
                                            _Float16* __restrict__ Vth) {
    __shared__ float tile[128 * 33];                  // [src_row][33] padded
    const int bid = blockIdx.x;
    const int t = threadIdx.x;

    if (bid < 512) {
        // ---- kprep: tile = full 128 d x 32 c ----
        int c0 = (bid & 63) * 32, kv = bid >> 6;
        const float* src = ktc + (size_t)kv * HDIM * CACHE + c0;
#pragma unroll
        for (int i = 0; i < 4; i++) {
            int idx = t + 256 * i;                    // 0..1023
            int d = idx >> 3, cc = idx & 7;           // 8 chunks of 4 c
            float4 v = *(const float4*)(src + (size_t)d * CACHE + cc * 4);
            *(float4*)(&tile[d * 33 + cc * 4]) = v;   // tile[d][c]
        }
        __syncthreads();
        _Float16* dst = Kh + ((size_t)kv * CTX_TOT + c0) * HDIM;
#pragma unroll
        for (int i = 0; i < 2; i++) {
            int c = (t >> 4) + 16 * i, dg = t & 15;   // lane writes 8 d (16B)
            half8 o;
#pragma unroll
            for (int k = 0; k < 8; k++) o[k] = (_Float16)tile[(dg * 8 + k) * 33 + c];
            *(half8*)(dst + (size_t)c * HDIM + dg * 8) = o;
        }
    } else if (bid < 1024) {
        // ---- vprep: tile = 128 c x 32 d ----
        int l = bid - 512;
        int c1 = (l & 15) * 128, d0 = ((l >> 4) & 3) * 32, kv = l >> 6;
        const float* src = vc + ((size_t)kv * CACHE + c1) * HDIM + d0;
#pragma unroll
        for (int i = 0; i < 4; i++) {
            int idx = t + 256 * i;
            int c = idx >> 3, dc = idx & 7;
            float4 v = *(const float4*)(src + (size_t)c * HDIM + dc * 4);
            *(float4*)(&tile[c * 33 + dc * 4]) = v;   // tile[c][d]
        }
        __syncthreads();
        _Float16* dst = Vth + ((size_t)kv * HDIM + d0) * CTX_TOT + c1;
#pragma unroll
        for (int i = 0; i < 2; i++) {
            int d = (t >> 4) + 16 * i, cg = t & 15;   // lane writes 8 c (16B)
            half8 o;
#pragma unroll
            for (int k = 0; k < 8; k++) o[k] = (_Float16)tile[(cg * 8 + k) * 33 + d];
            *(half8*)(dst + (size_t)d * CTX_TOT + cg * 8) = o;
        }
    } else if (bid < 1536) {
        // ---- knew: 4 f32 per thread ----
        int base = ((bid - 1024) * 256 + t) * 4;      // 0..2097151, 4-aligned
        float s = kq[0];
        float4 v = *(const float4*)(keys + base);
        v.x *= s; v.y *= s; v.z *= s; v.w *= s;
        *(float4*)(outk + base) = v;
        int kv = base >> 16;
        int rem = base & 0xFFFF;
        _Float16* dst = Kh + ((size_t)kv * CTX_TOT + CACHE) * HDIM + rem;
        dst[0] = (_Float16)v.x; dst[1] = (_Float16)v.y;
        dst[2] = (_Float16)v.z; dst[3] = (_Float16)v.w;
    } else {
        // ---- vnew: tile = 128 b x 32 d, clamp + outv in phase 1 ----
        int l = bid - 1536;
        int b1 = (l & 3) * 128, d0 = ((l >> 2) & 3) * 32, kv = l >> 4;
        const float* src = values + ((size_t)kv * BATCH + b1) * HDIM + d0;
        float* dst32 = outv + ((size_t)kv * BATCH + b1) * HDIM + d0;
#pragma unroll
        for (int i = 0; i < 4; i++) {
            int idx = t + 256 * i;
            int b = idx >> 3, dc = idx & 7;
            float4 v = *(const float4*)(src + (size_t)b * HDIM + dc * 4);
            v.x = fmaxf(v.x, -10000.0f); v.y = fmaxf(v.y, -10000.0f);
            v.z = fmaxf(v.z, -10000.0f); v.w = fmaxf(v.w, -10000.0f);
            *(float4*)(dst32 + (size_t)b * HDIM + dc * 4) = v;
            *(float4*)(&tile[b * 33 + dc * 4]) = v;   // tile[b][d]
        }
        __syncthreads();
        _Float16* dst = Vth + ((size_t)kv * HDIM + d0) * CTX_TOT + CACHE + b1;
#pragma unroll
        for (int i = 0; i < 2; i++) {
            int d = (t >> 4) + 16 * i, bg = t & 15;   // lane writes 8 b (16B)
            half8 o;
#pragma unroll
            for (int k = 0; k < 8; k++) o[k] = (_Float16)tile[(bg * 8 + k) * 33 + d];
            *(half8*)(dst + (size_t)d * CTX_TOT + bg * 8) = o;
        }
    }
}

// ================= split flash-attention kernel =================
// grid (128, SPLITS): blockIdx.x = h + 32*qb2 (128-row q block), blockIdx.y = s
// Each wave: 2 q sub-tiles (rows [qr0,qr0+15], [qr0+64,qr0+79]); S sequential
// per half (r9 register shape). NEW: staggered split-phase staging —
//   QK(t)[K] -> barrier1 (drains V-DMA(t), flew during QK) -> issue K-DMA(t+1)
//   -> softmax+PV(t)[V] -> barrier2 (drains K-DMA(t+1), flew during PV)
//   -> issue V-DMA(t+1)
// Same CT=64, same 50 KB LDS, same 2 barriers/tile as r9, but every DMA has a
// full compute phase in flight before its drain (r10's CT=32 dbuf doubled the
// per-tile overheads instead and regressed; r11's fixed-max softmax NaN'd —
// cache keys are UNSCALED in the reference, scores sigma~16 in log2 domain).
__global__ __launch_bounds__(256, 3) void attn_split(const float* __restrict__ q_g,
                                                     const _Float16* __restrict__ Kh,
                                                     const _Float16* __restrict__ Vth,
                                                     _Float16* __restrict__ Opart,
                                                     float* __restrict__ MLpart) {
    __shared__ _Float16 Klds[CT * KPITCH];          // [c][d] swizzled, 16384 B
    __shared__ _Float16 Vlds[HDIM * VPITCH];        // [d][c] swizzled, 16384 B
    __shared__ _Float16 Plds[4][32 * PPITCH];       // per-wave, 2 halves x 16 q, 18432 B

    const int h = blockIdx.x & 31;
    const int qb2 = blockIdx.x >> 5;                  // 0..3 (128-row blocks)
    const int s = blockIdx.y;                         // 0..5
    const int kv = h >> 2;
    const int t = threadIdx.x;
    const int wave = t >> 6;
    const int lane = t & 63;
    const int l15 = lane & 15, quad = lane >> 4;

    const float LOG2E = 1.44269504088896340736f;
    const int qrow0 = qb2 * 128 + wave * 16;          // half0; half1 = +64

    const _Float16* kg = Kh + (size_t)kv * CTX_TOT * HDIM;
    const _Float16* vg = Vth + (size_t)kv * HDIM * CTX_TOT;

    half8 qfrag[2][4];
#pragma unroll
    for (int hh = 0; hh < 2; hh++) {
        const float* qp = q_g + ((size_t)h * BATCH + qrow0 + hh * 64 + l15) * HDIM + quad * 8;
#pragma unroll
        for (int kb = 0; kb < 4; kb++) {
            const float* p = qp + kb * 32;
            float4 a = *(const float4*)p;
            float4 b = *(const float4*)(p + 4);
            qfrag[hh][kb][0] = (_Float16)(a.x * LOG2E); qfrag[hh][kb][1] = (_Float16)(a.y * LOG2E);
            qfrag[hh][kb][2] = (_Float16)(a.z * LOG2E); qfrag[hh][kb][3] = (_Float16)(a.w * LOG2E);
            qfrag[hh][kb][4] = (_Float16)(b.x * LOG2E); qfrag[hh][kb][5] = (_Float16)(b.y * LOG2E);
            qfrag[hh][kb][6] = (_Float16)(b.z * LOG2E); qfrag[hh][kb][7] = (_Float16)(b.w * LOG2E);
        }
    }

    floatx4 O[2][8];
#pragma unroll
    for (int hh = 0; hh < 2; hh++)
#pragma unroll
        for (int nb = 0; nb < 8; nb++) O[hh][nb] = (floatx4){0.f, 0.f, 0.f, 0.f};
    float m_r[2][4], l_r[2][4];
#pragma unroll
    for (int hh = 0; hh < 2; hh++)
#pragma unroll
        for (int r = 0; r < 4; r++) { m_r[hh][r] = NEG_BIG; l_r[hh][r] = 0.f; }

    const int nT = 34 + 2 * qb2;

    // ---- staging helpers (all waves participate; per-wave LDS slices) ----
    auto stageK = [&](int ttile) {
        const int c0s = ttile * CT;
#pragma unroll
        for (int j = 0; j < 4; j++) {
            int row = wave * 16 + j * 4 + (lane >> 4);        // 0..63
            int gch = (lane & 15) ^ (row & 7);                // swizzled global chunk
            dma16(kg + (size_t)(c0s + row) * HDIM + gch * 8,
                  &Klds[(wave * 16 + j * 4) * KPITCH]);
        }
    };
    auto stageV = [&](int ttile) {
        const int c0s = ttile * CT;
#pragma unroll
        for (int j = 0; j < 4; j++) {
            int row = wave * 32 + j * 8 + (lane >> 3);        // 0..127
            int gch = (lane & 7) ^ (row & 7);
            dma16(vg + (size_t)row * CTX_TOT + c0s + gch * 8,
                  &Vlds[(wave * 32 + j * 8) * VPITCH]);
        }
    };

    // ---- prologue: stage tile s fully, drain once ----
    stageK(s);
    stageV(s);
    __syncthreads();

    for (int tt = s; tt < nT; tt += SPLITS) {
        const int c0 = tt * CT;
        const bool active = (c0 <= CACHE + qrow0 + 64 + 15);

        // ======== Phase 1: QK^T + softmax + P (reads Klds only) ========
        if (active) {
#pragma unroll
            for (int hh = 0; hh < 2; hh++) {
                const int qr0h = qrow0 + hh * 64;
                if (c0 <= CACHE + qr0h + 15) {        // half active
                    floatx4 S[4];
#pragma unroll
                    for (int cs = 0; cs < 4; cs++) {
                        floatx4 a0 = (floatx4){0.f, 0.f, 0.f, 0.f};
                        int crow = cs * 16 + l15;
#pragma unroll
                        for (int kb = 0; kb < 4; kb++) {
                            half8 kf = *(const half8*)(&Klds[crow * KPITCH +
                                                             (((kb * 4 + quad) ^ (crow & 7)) << 3)]);
                            a0 = __builtin_amdgcn_mfma_f32_16x16x32_f16(qfrag[hh][kb], kf, a0, 0, 0, 0);
                        }
                        S[cs] = a0;
                    }
                    // mask (only near-diagonal tiles)
                    if (c0 + CT > CACHE + qr0h) {
#pragma unroll
                        for (int cs = 0; cs < 4; cs++)
#pragma unroll
                            for (int r = 0; r < 4; r++) {
                                int c = c0 + cs * 16 + l15;
                                if (c > CACHE + qr0h + quad * 4 + r) S[cs][r] = NEG_BIG;
                            }
                    }
                    float tmax[4];
#pragma unroll
                    for (int r = 0; r < 4; r++)
                        tmax[r] = fmaxf(fmaxf(S[0][r], S[1][r]), fmaxf(S[2][r], S[3][r]));
#pragma unroll
                    for (int off = 8; off >= 1; off >>= 1)
#pragma unroll
                        for (int r = 0; r < 4; r++)
                            tmax[r] = fmaxf(tmax[r], __shfl_xor(tmax[r], off, 64));
                    // rescale only when some row's max actually rose
                    bool ch = false;
#pragma unroll
                    for (int r = 0; r < 4; r++) ch = ch || (tmax[r] > m_r[hh][r]);
                    if (__any(ch)) {
#pragma unroll
                        for (int r = 0; r < 4; r++) {
                            float mn = fmaxf(m_r[hh][r], tmax[r]);
                            float alpha = __builtin_amdgcn_exp2f(m_r[hh][r] - mn);
                            m_r[hh][r] = mn;
                            l_r[hh][r] *= alpha;
#pragma unroll
                            for (int nb = 0; nb < 8; nb++) O[hh][nb][r] *= alpha;
                        }
                    }
#pragma unroll
                    for (int cs = 0; cs < 4; cs++)
#pragma unroll
                        for (int r = 0; r < 4; r++) {
                            float p = __builtin_amdgcn_exp2f(S[cs][r] - m_r[hh][r]);
                            l_r[hh][r] += p;
                            Plds[wave][(hh * 16 + quad * 4 + r) * PPITCH + cs * 16 + l15] = (_Float16)p;
                        }
                } else {
                    // half fully masked this tile: zero its P slab
#pragma unroll
                    for (int cs = 0; cs < 4; cs++)
#pragma unroll
                        for (int r = 0; r < 4; r++)
                            Plds[wave][(hh * 16 + quad * 4 + r) * PPITCH + cs * 16 + l15] = (_Float16)0.f;
                }
            }
        }

        __syncthreads();          // all K reads done; drains V-DMA(t) (issued last iter)
        if (tt + SPLITS < nT) stageK(tt + SPLITS);    // flies during PV phase

        // ======== Phase 2: O += P V (reads Vlds only) ========
        if (active) {
#pragma unroll
            for (int kb2 = 0; kb2 < 2; kb2++) {
                half8 pf0 = *(const half8*)(&Plds[wave][l15 * PPITCH + kb2 * 32 + quad * 8]);
                half8 pf1 = *(const half8*)(&Plds[wave][(16 + l15) * PPITCH + kb2 * 32 + quad * 8]);
#pragma unroll
                for (int nb = 0; nb < 8; nb++) {
                    int vrow = nb * 16 + l15;
                    half8 vf = *(const half8*)(&Vlds[vrow * VPITCH +
                                                     (((kb2 * 4 + quad) ^ (vrow & 7)) << 3)]);
                    O[0][nb] = __builtin_amdgcn_mfma_f32_16x16x32_f16(pf0, vf, O[0][nb], 0, 0, 0);
                    O[1][nb] = __builtin_amdgcn_mfma_f32_16x16x32_f16(pf1, vf, O[1][nb], 0, 0, 0);
                }
            }
        }

        __syncthreads();          // all V reads done; drains K-DMA(t+1) (flew during PV)
        if (tt + SPLITS < nT) stageV(tt + SPLITS);    // flies during next QK phase
    }

    // ---- epilogue: reduce l across column lanes; write f16 partials + (m,l) ----
#pragma unroll
    for (int hh = 0; hh < 2; hh++)
#pragma unroll
        for (int off = 8; off >= 1; off >>= 1)
#pragma unroll
            for (int r = 0; r < 4; r++) l_r[hh][r] += __shfl_xor(l_r[hh][r], off, 64);

    const size_t rowbase = (size_t)s * NHEADS * BATCH + (size_t)h * BATCH;
#pragma unroll
    for (int hh = 0; hh < 2; hh++) {
#pragma unroll
        for (int nb = 0; nb < 8; nb++)
#pragma unroll
            for (int r = 0; r < 4; r++) {
                int brow = qrow0 + hh * 64 + quad * 4 + r;
                Opart[(rowbase + brow) * HDIM + nb * 16 + l15] = (_Float16)O[hh][nb][r];
            }
        if (l15 == 0) {
#pragma unroll
            for (int r = 0; r < 4; r++) {
                int brow = qrow0 + hh * 64 + quad * 4 + r;
                MLpart[(rowbase + brow) * 2 + 0] = m_r[hh][r];
                MLpart[(rowbase + brow) * 2 + 1] = l_r[hh][r];
            }
        }
    }
}

// ================= merge kernel =================
// 8192 blocks x 256 threads; each block merges 2 rows x 128 d over SPLITS
__global__ __launch_bounds__(256) void attn_merge(const _Float16* __restrict__ Opart,
                                                  const float* __restrict__ MLpart,
                                                  float* __restrict__ out) {
    const int t = threadIdx.x;
    const int row = blockIdx.x * 2 + (t >> 7);
    const int d = t & 127;
    const size_t stride = (size_t)NHEADS * BATCH;     // 16384 rows per split

    float m[SPLITS], l[SPLITS];
    float mm = NEG_BIG;
#pragma unroll
    for (int s = 0; s < SPLITS; s++) {
        m[s] = MLpart[((size_t)s * stride + row) * 2];
        l[s] = MLpart[((size_t)s * stride + row) * 2 + 1];
        mm = fmaxf(mm, m[s]);
    }
    float denom = 0.f, acc = 0.f;
#pragma unroll
    for (int s = 0; s < SPLITS; s++) {
        float w = __builtin_amdgcn_exp2f(m[s] - mm);
        denom += w * l[s];
        acc += w * (float)Opart[((size_t)s * stride + row) * HDIM + d];
    }
    out[(size_t)row * HDIM + d] = acc / denom;
}

// ================= launch =================
extern "C" void kernel_launch(void* const* d_in, const int* in_sizes, int n_in,
                              void* d_out, int out_size, void* d_ws, size_t ws_size,
                              hipStream_t stream) {
    const float* queries = (const float*)d_in[0];
    const float* keys    = (const float*)d_in[1];
    const float* ktc     = (const float*)d_in[2];
    const float* values  = (const float*)d_in[3];
    const float* vcache  = (const float*)d_in[4];
    // d_in[5] = attn_bias: analytic causal mask, not read
    const float* kq      = (const float*)d_in[6];

    float* out     = (float*)d_out;
    float* out_sk  = out + (size_t)NHEADS * BATCH * HDIM;              // scaled_keys
    float* out_sv  = out_sk + (size_t)NKV * BATCH * HDIM;              // scaled_values

    _Float16* Kh   = (_Float16*)d_ws;                                  // [8][2560][128]
    _Float16* Vth  = Kh + (size_t)NKV * CTX_TOT * HDIM;                // [8][128][2560]
    _Float16* Opart = Vth + (size_t)NKV * HDIM * CTX_TOT;              // [6][16384][128] f16
    float*    MLpart = (float*)(Opart + (size_t)SPLITS * NHEADS * BATCH * HDIM); // [6][16384][2]

    prep<<<dim3(1664), dim3(256), 0, stream>>>(ktc, vcache, keys, values, kq,
                                               out_sk, out_sv, Kh, Vth);
    attn_split<<<dim3(128, SPLITS), dim3(256), 0, stream>>>(queries, Kh, Vth, Opart, MLpart);
    attn_merge<<<dim3(8192), dim3(256), 0, stream>>>(Opart, MLpart, out);
}